// Round 2
// baseline (306.600 us; speedup 1.0000x reference)
//
#include <hip/hip_runtime.h>
#include <hip/hip_bf16.h>

using bf16x8 = __attribute__((ext_vector_type(8))) short;
using f32x4  = __attribute__((ext_vector_type(4))) float;

__device__ __forceinline__ short f2bf(float f) {
  union { float f; unsigned u; } v; v.f = f;
  unsigned r = (v.u + 0x7FFFu + ((v.u >> 16) & 1u)) >> 16;
  return (short)(unsigned short)r;
}

// load 8 consecutive fp32 and round to bf16x8
__device__ __forceinline__ bf16x8 ld8f(const float* __restrict__ p) {
  float4 lo = *(const float4*)p;
  float4 hi = *(const float4*)(p + 4);
  bf16x8 r;
  r[0] = f2bf(lo.x); r[1] = f2bf(lo.y); r[2] = f2bf(lo.z); r[3] = f2bf(lo.w);
  r[4] = f2bf(hi.x); r[5] = f2bf(hi.y); r[6] = f2bf(hi.z); r[7] = f2bf(hi.w);
  return r;
}

#define BM 128
#define BN 128
#define BKSTEP 32
#define LDK 40   // 32 + 8 pad elems; 80B row stride

// C = A[M,K] * B[N,K]^T, A/B fp32 (converted to bf16 for MFMA).
// MODE 0: fp32 C to outC.
// MODE 1: QKV epilogue — l2norm q,k rows (d=64 per wave-col-slice), temp folded into q,
//         scatter bf16 Q[b,h,n,d], K[b,h,n,d], Vt[b,h,d,n].
template<int MODE>
__global__ __launch_bounds__(256, 2)
void gemm_bt(const float* __restrict__ A, const float* __restrict__ B,
             short* __restrict__ outQ, short* __restrict__ outK, short* __restrict__ outVt,
             float* __restrict__ outC,
             const float* __restrict__ temp,
             int M, int N, int Kd)
{
  __shared__ short As[BM * LDK];
  __shared__ short Bs[BN * LDK];
  const int tid  = threadIdx.x;
  const int lane = tid & 63;
  const int w    = tid >> 6;
  const int wr   = w >> 1, wc = w & 1;
  const int fr   = lane & 15, fq = lane >> 4;
  const int bm = blockIdx.y, bn = blockIdx.x;
  const int rowA = bm * BM, rowB = bn * BN;
  const int sr = tid >> 2;
  const int sc = (tid & 3) * 8;

  f32x4 acc[4][4];
  #pragma unroll
  for (int m = 0; m < 4; ++m)
    #pragma unroll
    for (int n = 0; n < 4; ++n) acc[m][n] = (f32x4){0.f, 0.f, 0.f, 0.f};

  for (int k0 = 0; k0 < Kd; k0 += BKSTEP) {
    bf16x8 a0 = ld8f(A + (size_t)(rowA + sr)      * Kd + k0 + sc);
    bf16x8 a1 = ld8f(A + (size_t)(rowA + 64 + sr) * Kd + k0 + sc);
    bf16x8 b0 = ld8f(B + (size_t)(rowB + sr)      * Kd + k0 + sc);
    bf16x8 b1 = ld8f(B + (size_t)(rowB + 64 + sr) * Kd + k0 + sc);
    __syncthreads();   // WAR: previous iter's frag reads done before overwrite
    *(bf16x8*)(As + sr * LDK + sc)        = a0;
    *(bf16x8*)(As + (64 + sr) * LDK + sc) = a1;
    *(bf16x8*)(Bs + sr * LDK + sc)        = b0;
    *(bf16x8*)(Bs + (64 + sr) * LDK + sc) = b1;
    __syncthreads();
    bf16x8 afr[4], bfr[4];
    #pragma unroll
    for (int m = 0; m < 4; ++m)
      afr[m] = *(const bf16x8*)(As + (wr*64 + m*16 + fr) * LDK + fq*8);
    #pragma unroll
    for (int n = 0; n < 4; ++n)
      bfr[n] = *(const bf16x8*)(Bs + (wc*64 + n*16 + fr) * LDK + fq*8);
    #pragma unroll
    for (int m = 0; m < 4; ++m)
      #pragma unroll
      for (int n = 0; n < 4; ++n)
        acc[m][n] = __builtin_amdgcn_mfma_f32_16x16x32_bf16(afr[m], bfr[n], acc[m][n], 0, 0, 0);
  }

  if (MODE == 0) {
    #pragma unroll
    for (int m = 0; m < 4; ++m) {
      int r0 = rowA + wr*64 + m*16 + fq*4;
      #pragma unroll
      for (int n = 0; n < 4; ++n) {
        int c = rowB + wc*64 + n*16 + fr;
        #pragma unroll
        for (int r = 0; r < 4; ++r)
          outC[(size_t)(r0 + r) * N + c] = acc[m][n][r];
      }
    }
  } else {
    // wave owns cols [gc0, gc0+64) -> one (t3, h) slice of qkv
    const int gc0   = rowB + wc*64;
    const int slice = gc0 >> 6;      // 0..23
    const int t3    = slice >> 3;    // 0=q,1=k,2=v
    const int h     = slice & 7;
    if (t3 < 2) {
      float scl[4][4];
      const float tval = (t3 == 0) ? temp[h] : 1.0f;
      #pragma unroll
      for (int m = 0; m < 4; ++m) {
        #pragma unroll
        for (int r = 0; r < 4; ++r) {
          float ss = 0.f;
          #pragma unroll
          for (int n = 0; n < 4; ++n) ss += acc[m][n][r] * acc[m][n][r];
          #pragma unroll
          for (int off = 1; off < 16; off <<= 1) ss += __shfl_xor(ss, off);
          scl[m][r] = tval / fmaxf(sqrtf(ss), 1e-12f);
        }
      }
      short* dst = (t3 == 0) ? outQ : outK;
      #pragma unroll
      for (int m = 0; m < 4; ++m) {
        #pragma unroll
        for (int r = 0; r < 4; ++r) {
          int rg = rowA + wr*64 + m*16 + fq*4 + r;
          int b = rg >> 11, nn = rg & 2047;
          size_t rowoff = ((size_t)(b*8 + h) * 2048 + nn) * 64;
          #pragma unroll
          for (int n = 0; n < 4; ++n)
            dst[rowoff + n*16 + fr] = f2bf(acc[m][n][r] * scl[m][r]);
        }
      }
    } else {
      #pragma unroll
      for (int m = 0; m < 4; ++m) {
        #pragma unroll
        for (int r = 0; r < 4; ++r) {
          int rg = rowA + wr*64 + m*16 + fq*4 + r;
          int b = rg >> 11, nn = rg & 2047;
          #pragma unroll
          for (int n = 0; n < 4; ++n)
            outVt[((size_t)(b*8 + h) * 64 + n*16 + fr) * 2048 + nn] = f2bf(acc[m][n][r]);
        }
      }
    }
  }
}

#define LDP 72   // 16x64 P tile padded: 144B row stride

__global__ __launch_bounds__(256, 2)
void attn_fwd(const short* __restrict__ Q, const short* __restrict__ Kt,
              const short* __restrict__ Vt, float* __restrict__ AO)
{
  __shared__ short Pl[4][16 * LDP];
  const int tid  = threadIdx.x;
  const int lane = tid & 63;
  const int w    = tid >> 6;
  const int fr   = lane & 15, fq = lane >> 4;
  const int bh = blockIdx.y;          // b*8+h
  const int qt = blockIdx.x;          // q tile of 64
  const int b = bh >> 3, h = bh & 7;
  const size_t base  = (size_t)bh * 2048 * 64;  // Q,K: [bh][n][64]
  const size_t vbase = (size_t)bh * 64 * 2048;  // Vt:  [bh][64][n]
  const int q0 = qt * 64 + w * 16;

  bf16x8 aq[2];
  #pragma unroll
  for (int j = 0; j < 2; ++j)
    aq[j] = *(const bf16x8*)(Q + base + (size_t)(q0 + fr) * 64 + j*32 + fq*8);

  f32x4 o[4];
  #pragma unroll
  for (int db = 0; db < 4; ++db) o[db] = (f32x4){0.f, 0.f, 0.f, 0.f};
  float mrun[4] = {-1e30f, -1e30f, -1e30f, -1e30f};
  float lrun[4] = {0.f, 0.f, 0.f, 0.f};

  for (int t = 0; t < 32; ++t) {
    const int k0 = t * 64;
    f32x4 s[4];
    #pragma unroll
    for (int nb = 0; nb < 4; ++nb) {
      bf16x8 bk0 = *(const bf16x8*)(Kt + base + (size_t)(k0 + nb*16 + fr) * 64 + fq*8);
      bf16x8 bk1 = *(const bf16x8*)(Kt + base + (size_t)(k0 + nb*16 + fr) * 64 + 32 + fq*8);
      f32x4 z = (f32x4){0.f, 0.f, 0.f, 0.f};
      z = __builtin_amdgcn_mfma_f32_16x16x32_bf16(aq[0], bk0, z, 0, 0, 0);
      z = __builtin_amdgcn_mfma_f32_16x16x32_bf16(aq[1], bk1, z, 0, 0, 0);
      s[nb] = z;
    }
    float mnew[4];
    #pragma unroll
    for (int r = 0; r < 4; ++r) {
      float mx = fmaxf(fmaxf(s[0][r], s[1][r]), fmaxf(s[2][r], s[3][r]));
      #pragma unroll
      for (int off = 1; off < 16; off <<= 1) mx = fmaxf(mx, __shfl_xor(mx, off));
      mnew[r] = fmaxf(mrun[r], mx);
      float corr = __expf(mrun[r] - mnew[r]);
      lrun[r] *= corr;
      #pragma unroll
      for (int db = 0; db < 4; ++db) o[db][r] *= corr;
      mrun[r] = mnew[r];
    }
    #pragma unroll
    for (int nb = 0; nb < 4; ++nb)
      #pragma unroll
      for (int r = 0; r < 4; ++r)
        s[nb][r] = __expf(s[nb][r] - mnew[r]);
    #pragma unroll
    for (int r = 0; r < 4; ++r) {
      float sm = s[0][r] + s[1][r] + s[2][r] + s[3][r];
      #pragma unroll
      for (int off = 1; off < 16; off <<= 1) sm += __shfl_xor(sm, off);
      lrun[r] += sm;
    }
    __syncthreads();   // order P reads (prev iter) before overwrite
    short* pw = &Pl[w][0];
    #pragma unroll
    for (int nb = 0; nb < 4; ++nb)
      #pragma unroll
      for (int r = 0; r < 4; ++r)
        pw[(fq*4 + r) * LDP + nb*16 + fr] = f2bf(s[nb][r]);
    __syncthreads();   // P visible before A-frag reads
    bf16x8 pa[2];
    #pragma unroll
    for (int j = 0; j < 2; ++j)
      pa[j] = *(const bf16x8*)(pw + fr * LDP + j*32 + fq*8);
    #pragma unroll
    for (int db = 0; db < 4; ++db) {
      bf16x8 bv0 = *(const bf16x8*)(Vt + vbase + (size_t)(db*16 + fr) * 2048 + k0 + fq*8);
      bf16x8 bv1 = *(const bf16x8*)(Vt + vbase + (size_t)(db*16 + fr) * 2048 + k0 + 32 + fq*8);
      o[db] = __builtin_amdgcn_mfma_f32_16x16x32_bf16(pa[0], bv0, o[db], 0, 0, 0);
      o[db] = __builtin_amdgcn_mfma_f32_16x16x32_bf16(pa[1], bv1, o[db], 0, 0, 0);
    }
  }
  #pragma unroll
  for (int db = 0; db < 4; ++db)
    #pragma unroll
    for (int r = 0; r < 4; ++r) {
      int row = b * 2048 + q0 + fq*4 + r;
      int col = h * 64 + db*16 + fr;
      AO[(size_t)row * 512 + col] = o[db][r] / lrun[r];
    }
}

extern "C" void kernel_launch(void* const* d_in, const int* in_sizes, int n_in,
                              void* d_out, int out_size, void* d_ws, size_t ws_size,
                              hipStream_t stream)
{
  const float* x     = (const float*)d_in[0];   // [4,2048,512] fp32
  const float* w_qkv = (const float*)d_in[1];   // [1536,512]  fp32
  const float* w_out = (const float*)d_in[2];   // [512,512]   fp32
  const float* temp  = (const float*)d_in[3];   // [8,1,1]     fp32
  float* out = (float*)d_out;                   // [4,2048,512] fp32
  short* ws  = (short*)d_ws;

  const size_t NQ = (size_t)4 * 8 * 2048 * 64;  // 4194304 elems per tensor
  short* Qb  = ws;                    // bf16 [b,h,n,64] normalized q * temp[h]
  short* Kb  = ws + NQ;               // bf16 [b,h,n,64] normalized k
  short* Vtb = ws + 2 * NQ;           // bf16 [b,h,64,n]
  float* AOb = (float*)(ws + 3 * NQ); // fp32 [8192,512] attention output

  gemm_bt<1><<<dim3(12, 64), 256, 0, stream>>>(x, w_qkv, Qb, Kb, Vtb, nullptr, temp,
                                               8192, 1536, 512);
  attn_fwd<<<dim3(32, 32), 256, 0, stream>>>(Qb, Kb, Vtb, AOb);
  gemm_bt<0><<<dim3(4, 64), 256, 0, stream>>>(AOb, w_out, nullptr, nullptr, nullptr, out,
                                              nullptr, 8192, 512, 512);
}

// Round 3
// 301.716 us; speedup vs baseline: 1.0162x; 1.0162x over previous
//
#include <hip/hip_runtime.h>
#include <hip/hip_bf16.h>

using bf16x8 = __attribute__((ext_vector_type(8))) short;
using f32x4  = __attribute__((ext_vector_type(4))) float;

__device__ __forceinline__ short f2bf(float f) {
  union { float f; unsigned u; } v; v.f = f;
  unsigned r = (v.u + 0x7FFFu + ((v.u >> 16) & 1u)) >> 16;
  return (short)(unsigned short)r;
}

// pack two f32 -> two bf16 (RNE) in one HW op
__device__ __forceinline__ unsigned cvtpk(float lo, float hi) {
  unsigned r;
  asm("v_cvt_pk_bf16_f32 %0, %1, %2" : "=v"(r) : "v"(lo), "v"(hi));
  return r;
}

// load 8 consecutive fp32 and round to bf16x8
__device__ __forceinline__ bf16x8 ld8f(const float* __restrict__ p) {
  float4 lo = *(const float4*)p;
  float4 hi = *(const float4*)(p + 4);
  bf16x8 r;
  r[0] = f2bf(lo.x); r[1] = f2bf(lo.y); r[2] = f2bf(lo.z); r[3] = f2bf(lo.w);
  r[4] = f2bf(hi.x); r[5] = f2bf(hi.y); r[6] = f2bf(hi.z); r[7] = f2bf(hi.w);
  return r;
}

#define BM 128
#define BN 128
#define BKSTEP 32
#define LDK 40   // 32 + 8 pad elems; 80B row stride

// C = A[M,K] * B[N,K]^T, A/B fp32 (converted to bf16 for MFMA).
// MODE 0: fp32 C to outC.
// MODE 1: QKV epilogue — l2norm q,k rows, temp folded into q,
//         scatter bf16 Q[b,h,n,d], K[b,h,n,d], Vt[b,h,d,n].
template<int MODE>
__global__ __launch_bounds__(256, 2)
void gemm_bt(const float* __restrict__ A, const float* __restrict__ B,
             short* __restrict__ outQ, short* __restrict__ outK, short* __restrict__ outVt,
             float* __restrict__ outC,
             const float* __restrict__ temp,
             int M, int N, int Kd)
{
  __shared__ short As[BM * LDK];
  __shared__ short Bs[BN * LDK];
  const int tid  = threadIdx.x;
  const int lane = tid & 63;
  const int w    = tid >> 6;
  const int wr   = w >> 1, wc = w & 1;
  const int fr   = lane & 15, fq = lane >> 4;
  const int bm = blockIdx.y, bn = blockIdx.x;
  const int rowA = bm * BM, rowB = bn * BN;
  const int sr = tid >> 2;
  const int sc = (tid & 3) * 8;

  f32x4 acc[4][4];
  #pragma unroll
  for (int m = 0; m < 4; ++m)
    #pragma unroll
    for (int n = 0; n < 4; ++n) acc[m][n] = (f32x4){0.f, 0.f, 0.f, 0.f};

  for (int k0 = 0; k0 < Kd; k0 += BKSTEP) {
    bf16x8 a0 = ld8f(A + (size_t)(rowA + sr)      * Kd + k0 + sc);
    bf16x8 a1 = ld8f(A + (size_t)(rowA + 64 + sr) * Kd + k0 + sc);
    bf16x8 b0 = ld8f(B + (size_t)(rowB + sr)      * Kd + k0 + sc);
    bf16x8 b1 = ld8f(B + (size_t)(rowB + 64 + sr) * Kd + k0 + sc);
    __syncthreads();   // WAR: previous iter's frag reads done before overwrite
    *(bf16x8*)(As + sr * LDK + sc)        = a0;
    *(bf16x8*)(As + (64 + sr) * LDK + sc) = a1;
    *(bf16x8*)(Bs + sr * LDK + sc)        = b0;
    *(bf16x8*)(Bs + (64 + sr) * LDK + sc) = b1;
    __syncthreads();
    bf16x8 afr[4], bfr[4];
    #pragma unroll
    for (int m = 0; m < 4; ++m)
      afr[m] = *(const bf16x8*)(As + (wr*64 + m*16 + fr) * LDK + fq*8);
    #pragma unroll
    for (int n = 0; n < 4; ++n)
      bfr[n] = *(const bf16x8*)(Bs + (wc*64 + n*16 + fr) * LDK + fq*8);
    #pragma unroll
    for (int m = 0; m < 4; ++m)
      #pragma unroll
      for (int n = 0; n < 4; ++n)
        acc[m][n] = __builtin_amdgcn_mfma_f32_16x16x32_bf16(afr[m], bfr[n], acc[m][n], 0, 0, 0);
  }

  if (MODE == 0) {
    #pragma unroll
    for (int m = 0; m < 4; ++m) {
      int r0 = rowA + wr*64 + m*16 + fq*4;
      #pragma unroll
      for (int n = 0; n < 4; ++n) {
        int c = rowB + wc*64 + n*16 + fr;
        #pragma unroll
        for (int r = 0; r < 4; ++r)
          outC[(size_t)(r0 + r) * N + c] = acc[m][n][r];
      }
    }
  } else {
    const int gc0   = rowB + wc*64;
    const int slice = gc0 >> 6;      // 0..23
    const int t3    = slice >> 3;    // 0=q,1=k,2=v
    const int h     = slice & 7;
    if (t3 < 2) {
      float scl[4][4];
      const float tval = (t3 == 0) ? temp[h] : 1.0f;
      #pragma unroll
      for (int m = 0; m < 4; ++m) {
        #pragma unroll
        for (int r = 0; r < 4; ++r) {
          float ss = 0.f;
          #pragma unroll
          for (int n = 0; n < 4; ++n) ss += acc[m][n][r] * acc[m][n][r];
          #pragma unroll
          for (int off = 1; off < 16; off <<= 1) ss += __shfl_xor(ss, off);
          scl[m][r] = tval / fmaxf(sqrtf(ss), 1e-12f);
        }
      }
      short* dst = (t3 == 0) ? outQ : outK;
      #pragma unroll
      for (int m = 0; m < 4; ++m) {
        #pragma unroll
        for (int r = 0; r < 4; ++r) {
          int rg = rowA + wr*64 + m*16 + fq*4 + r;
          int b = rg >> 11, nn = rg & 2047;
          size_t rowoff = ((size_t)(b*8 + h) * 2048 + nn) * 64;
          #pragma unroll
          for (int n = 0; n < 4; ++n)
            dst[rowoff + n*16 + fr] = f2bf(acc[m][n][r] * scl[m][r]);
        }
      }
    } else {
      #pragma unroll
      for (int m = 0; m < 4; ++m) {
        #pragma unroll
        for (int r = 0; r < 4; ++r) {
          int rg = rowA + wr*64 + m*16 + fq*4 + r;
          int b = rg >> 11, nn = rg & 2047;
          #pragma unroll
          for (int n = 0; n < 4; ++n)
            outVt[((size_t)(b*8 + h) * 64 + n*16 + fr) * 2048 + nn] = f2bf(acc[m][n][r]);
        }
      }
    }
  }
}

#define LDP 72   // 16x64 P tile padded: 144B row stride (16B aligned)

// Flash attention, swapped-QK^T layout: S^T = mfma(A=K, B=Q) so each lane
// holds 16 scores of ONE q-row (q = lane&15). Softmax = in-lane reduce +
// 2 shuffles. No __syncthreads: Pl is per-wave, LDS ops are in-order per wave.
__global__ __launch_bounds__(256, 2)
void attn_fwd(const short* __restrict__ Q, const short* __restrict__ Kt,
              const short* __restrict__ Vt, float* __restrict__ AO)
{
  __shared__ short Pl[4][16 * LDP];
  const int tid  = threadIdx.x;
  const int lane = tid & 63;
  const int w    = tid >> 6;
  const int fr   = lane & 15, fq = lane >> 4;
  const int bh = blockIdx.y;          // b*8+h
  const int qt = blockIdx.x;          // q tile of 64
  const int b = bh >> 3, h = bh & 7;
  const size_t base  = (size_t)bh * 2048 * 64;  // Q,K: [bh][n][64]
  const size_t vbase = (size_t)bh * 64 * 2048;  // Vt:  [bh][64][n]
  const int q0 = qt * 64 + w * 16;

  // Q fragment (B-operand): lane holds Q row q0+fr, d-elems fq*8..+7 (+32)
  bf16x8 bq[2];
  #pragma unroll
  for (int j = 0; j < 2; ++j)
    bq[j] = *(const bf16x8*)(Q + base + (size_t)(q0 + fr) * 64 + j*32 + fq*8);

  f32x4 o[4];
  #pragma unroll
  for (int db = 0; db < 4; ++db) o[db] = (f32x4){0.f, 0.f, 0.f, 0.f};
  float mrun = -1e30f;   // running max for q = q0+fr (dup across fq)
  float lrun = 0.f;      // running denom for q = q0+fr

  short* pw = &Pl[w][0];

  for (int t = 0; t < 32; ++t) {
    const int k0 = t * 64;
    // S^T tiles: A = K rows (k), B = Q rows (q).
    // Lane holds s[nb][r] = P[q=q0+fr][k = k0 + nb*16 + fq*4 + r]
    f32x4 s[4];
    #pragma unroll
    for (int nb = 0; nb < 4; ++nb) {
      bf16x8 ak0 = *(const bf16x8*)(Kt + base + (size_t)(k0 + nb*16 + fr) * 64 + fq*8);
      bf16x8 ak1 = *(const bf16x8*)(Kt + base + (size_t)(k0 + nb*16 + fr) * 64 + 32 + fq*8);
      f32x4 z = (f32x4){0.f, 0.f, 0.f, 0.f};
      z = __builtin_amdgcn_mfma_f32_16x16x32_bf16(ak0, bq[0], z, 0, 0, 0);
      z = __builtin_amdgcn_mfma_f32_16x16x32_bf16(ak1, bq[1], z, 0, 0, 0);
      s[nb] = z;
    }
    // tile max (in-lane over 16, then across the 4 fq replicas of this q)
    float mx = s[0][0];
    #pragma unroll
    for (int nb = 0; nb < 4; ++nb)
      #pragma unroll
      for (int r = 0; r < 4; ++r) mx = fmaxf(mx, s[nb][r]);
    mx = fmaxf(mx, __shfl_xor(mx, 16));
    mx = fmaxf(mx, __shfl_xor(mx, 32));
    // defer-max: rescale only if some row's max grew
    if (__any(mx > mrun)) {
      float mnew = fmaxf(mrun, mx);
      float corr = __expf(mrun - mnew);
      lrun *= corr;
      mrun = mnew;
      float c4[4];
      #pragma unroll
      for (int r = 0; r < 4; ++r) c4[r] = __shfl(corr, fq*4 + r, 16);
      #pragma unroll
      for (int db = 0; db < 4; ++db)
        #pragma unroll
        for (int r = 0; r < 4; ++r) o[db][r] *= c4[r];
    }
    // exponentiate + partial sum (in-lane), then 2 shuffles
    float ts = 0.f;
    #pragma unroll
    for (int nb = 0; nb < 4; ++nb)
      #pragma unroll
      for (int r = 0; r < 4; ++r) {
        float p = __expf(s[nb][r] - mrun);
        s[nb][r] = p;
        ts += p;
      }
    ts += __shfl_xor(ts, 16);
    ts += __shfl_xor(ts, 32);
    lrun += ts;
    // P write: 4 consecutive k per lane -> packed 8B writes, row = q-local = fr
    #pragma unroll
    for (int nb = 0; nb < 4; ++nb) {
      unsigned lo = cvtpk(s[nb][0], s[nb][1]);
      unsigned hi = cvtpk(s[nb][2], s[nb][3]);
      *(uint2*)(pw + fr * LDP + nb*16 + fq*4) = make_uint2(lo, hi);
    }
    // PV: A = P rows (q), B = Vt rows (d). In-order wave LDS -> no barrier.
    bf16x8 pa[2];
    #pragma unroll
    for (int j = 0; j < 2; ++j)
      pa[j] = *(const bf16x8*)(pw + fr * LDP + j*32 + fq*8);
    #pragma unroll
    for (int db = 0; db < 4; ++db) {
      bf16x8 bv0 = *(const bf16x8*)(Vt + vbase + (size_t)(db*16 + fr) * 2048 + k0 + fq*8);
      bf16x8 bv1 = *(const bf16x8*)(Vt + vbase + (size_t)(db*16 + fr) * 2048 + k0 + 32 + fq*8);
      o[db] = __builtin_amdgcn_mfma_f32_16x16x32_bf16(pa[0], bv0, o[db], 0, 0, 0);
      o[db] = __builtin_amdgcn_mfma_f32_16x16x32_bf16(pa[1], bv1, o[db], 0, 0, 0);
    }
  }
  // epilogue: lane's o rows are q = fq*4+r; fetch their denominators
  float l4[4];
  #pragma unroll
  for (int r = 0; r < 4; ++r) l4[r] = 1.0f / __shfl(lrun, fq*4 + r, 16);
  #pragma unroll
  for (int db = 0; db < 4; ++db)
    #pragma unroll
    for (int r = 0; r < 4; ++r) {
      int row = b * 2048 + q0 + fq*4 + r;
      int col = h * 64 + db*16 + fr;
      AO[(size_t)row * 512 + col] = o[db][r] * l4[r];
    }
}

extern "C" void kernel_launch(void* const* d_in, const int* in_sizes, int n_in,
                              void* d_out, int out_size, void* d_ws, size_t ws_size,
                              hipStream_t stream)
{
  const float* x     = (const float*)d_in[0];   // [4,2048,512] fp32
  const float* w_qkv = (const float*)d_in[1];   // [1536,512]  fp32
  const float* w_out = (const float*)d_in[2];   // [512,512]   fp32
  const float* temp  = (const float*)d_in[3];   // [8,1,1]     fp32
  float* out = (float*)d_out;                   // [4,2048,512] fp32
  short* ws  = (short*)d_ws;

  const size_t NQ = (size_t)4 * 8 * 2048 * 64;  // 4194304 elems per tensor
  short* Qb  = ws;                    // bf16 [b,h,n,64] normalized q * temp[h]
  short* Kb  = ws + NQ;               // bf16 [b,h,n,64] normalized k
  short* Vtb = ws + 2 * NQ;           // bf16 [b,h,64,n]
  float* AOb = (float*)(ws + 3 * NQ); // fp32 [8192,512] attention output

  gemm_bt<1><<<dim3(12, 64), 256, 0, stream>>>(x, w_qkv, Qb, Kb, Vtb, nullptr, temp,
                                               8192, 1536, 512);
  attn_fwd<<<dim3(32, 32), 256, 0, stream>>>(Qb, Kb, Vtb, AOb);
  gemm_bt<0><<<dim3(4, 64), 256, 0, stream>>>(AOb, w_out, nullptr, nullptr, nullptr, out,
                                              nullptr, 8192, 512, 512);
}